// Round 2
// baseline (838.028 us; speedup 1.0000x reference)
//
#include <hip/hip_runtime.h>

typedef unsigned short ushort_t;
typedef __attribute__((ext_vector_type(8))) short short8;
typedef __attribute__((ext_vector_type(4))) float floatx4;

#define T_TOK 8192
#define HDIM 1024
#define FDIM 2048
#define NEXP 8
#define TK_SLOTS (T_TOK * 2)

__device__ __forceinline__ float b2f(unsigned short u) {
    union { unsigned int i; float f; } x; x.i = ((unsigned int)u) << 16; return x.f;
}
__device__ __forceinline__ unsigned short f2b(float f) {  // RNE bf16
    unsigned int u = __float_as_uint(f);
    u += 0x7FFF + ((u >> 16) & 1);
    return (unsigned short)(u >> 16);
}
__device__ __forceinline__ void gload16(const void* g, void* l) {
    // async global->LDS, 16B/lane; LDS dest = wave-uniform base + lane*16
    __builtin_amdgcn_global_load_lds((const __attribute__((address_space(1))) void*)g,
                                     (__attribute__((address_space(3))) void*)l,
                                     16, 0, 0);
}

// ---------------- f32 -> bf16 conversion (8 elems/thread) ----------------
__global__ __launch_bounds__(256) void cvt_kernel(
    const float* __restrict__ src, ushort_t* __restrict__ dst, int n8)
{
    int i = blockIdx.x * 256 + threadIdx.x;
    if (i >= n8) return;
    const float4* s4 = (const float4*)src;
    float4 a = s4[2 * i], b = s4[2 * i + 1];
    short8 o;
    o[0] = (short)f2b(a.x); o[1] = (short)f2b(a.y);
    o[2] = (short)f2b(a.z); o[3] = (short)f2b(a.w);
    o[4] = (short)f2b(b.x); o[5] = (short)f2b(b.y);
    o[6] = (short)f2b(b.z); o[7] = (short)f2b(b.w);
    *(short8*)&dst[(size_t)i * 8] = o;
}

// ---------------- router: f32 logits, softmax, top-2, counts ----------------
__global__ __launch_bounds__(256) void router_kernel(
    const float* __restrict__ X, const float* __restrict__ GW,
    float* __restrict__ logits_out, int* __restrict__ tk_e,
    float* __restrict__ tk_w, int* __restrict__ counts)
{
    __shared__ __align__(16) float gw[NEXP * HDIM];   // 32 KB
    const int tid = threadIdx.x;
#pragma unroll
    for (int c = 0; c < 8; ++c) {
        int idx = (c * 256 + tid) * 4;
        *(float4*)&gw[idx] = *(const float4*)&GW[idx];
    }
    __syncthreads();
    const int w = tid >> 6, l = tid & 63;
    const int t = blockIdx.x * 4 + w;
    float acc[NEXP];
#pragma unroll
    for (int e = 0; e < NEXP; ++e) acc[e] = 0.f;
#pragma unroll
    for (int it = 0; it < 4; ++it) {
        const int colb = it * 256 + l * 4;
        float4 xv = *(const float4*)&X[(size_t)t * HDIM + colb];
#pragma unroll
        for (int e = 0; e < NEXP; ++e) {
            float4 gv = *(const float4*)&gw[e * HDIM + colb];
            acc[e] += xv.x * gv.x + xv.y * gv.y + xv.z * gv.z + xv.w * gv.w;
        }
    }
#pragma unroll
    for (int off = 32; off >= 1; off >>= 1)
#pragma unroll
        for (int e = 0; e < NEXP; ++e) acc[e] += __shfl_xor(acc[e], off, 64);

    if (l == 0) {
        float mx = acc[0];
#pragma unroll
        for (int e = 1; e < NEXP; ++e) mx = fmaxf(mx, acc[e]);
        float p[NEXP];
#pragma unroll
        for (int e = 0; e < NEXP; ++e) p[e] = __expf(acc[e] - mx);
        int e0 = 0;
#pragma unroll
        for (int e = 1; e < NEXP; ++e) if (p[e] > p[e0]) e0 = e;  // strict >: lower idx wins ties
        int e1 = (e0 == 0) ? 1 : 0;
#pragma unroll
        for (int e = 0; e < NEXP; ++e) if (e != e0 && p[e] > p[e1]) e1 = e;
        float den = p[e0] + p[e1];
        tk_e[t * 2] = e0; tk_e[t * 2 + 1] = e1;
        tk_w[t * 2] = p[e0] / den; tk_w[t * 2 + 1] = p[e1] / den;
        atomicAdd(&counts[e0], 1); atomicAdd(&counts[e1], 1);
#pragma unroll
        for (int e = 0; e < NEXP; ++e) logits_out[(size_t)t * NEXP + e] = acc[e];
    }
}

// ---------------- prefix over E=8 counts ----------------
__global__ void prefix_kernel(const int* __restrict__ counts,
                              int* __restrict__ offsets, int* __restrict__ cursors)
{
    if (threadIdx.x == 0) {
        int s = 0;
        for (int e = 0; e < NEXP; ++e) { offsets[e] = s; s += counts[e]; }
    }
    if (threadIdx.x < NEXP) cursors[threadIdx.x] = 0;
}

// ---------------- scatter tokens to compact per-expert lists ----------------
__global__ __launch_bounds__(256) void scatter_kernel(
    const int* __restrict__ tk_e, const float* __restrict__ tk_w,
    const int* __restrict__ offsets, int* __restrict__ cursors,
    int* __restrict__ token_list, float* __restrict__ weight_list,
    int* __restrict__ slot_of)
{
    int t = blockIdx.x * 256 + threadIdx.x;
    if (t >= T_TOK) return;
#pragma unroll
    for (int k = 0; k < 2; ++k) {
        int e = tk_e[t * 2 + k];
        int pos = atomicAdd(&cursors[e], 1);
        int slot = offsets[e] + pos;
        token_list[slot] = t;
        weight_list[slot] = tk_w[t * 2 + k];
        slot_of[t * 2 + k] = slot;
    }
}

// ---------------- grouped GEMM template (m97 structure), bf16 in/out ----------------
// C[m,n] = sum_k A[m,k] * W_e[n,k], 128x128 tile, BK=32, 4 waves at 64x64.
// MODE 0: Out = bf16(silu(acc))             (C1 = silu(X@w1^T))
// MODE 1: Out = bf16(acc * C1)              (G  = C1 * (X@w3^T)) -- may run in-place on C1
// MODE 2: Out = bf16(weight[row] * acc)     (Y  = w_route * (G@w2^T))
template <int MODE, int NDIM, int KDIM, bool GATHER>
__global__ __launch_bounds__(256) void moe_gemm(
    const ushort_t* __restrict__ A, const ushort_t* __restrict__ W,
    const int* __restrict__ counts, const int* __restrict__ offsets,
    const int* __restrict__ token_list, const float* __restrict__ weight_list,
    const ushort_t* C1, ushort_t* Out)   // no __restrict__: MODE 1 aliases C1 == Out
{
    const int e = blockIdx.z;
    const int ne = counts[e];
    const int m0 = blockIdx.y * 128;
    if (m0 >= ne) return;
    const int n0 = blockIdx.x * 128;
    const int aoff = offsets[e];
    const ushort_t* Bw = W + (size_t)e * NDIM * KDIM;

    __shared__ __align__(16) ushort_t As[128 * 32];
    __shared__ __align__(16) ushort_t Bs[128 * 32];

    const int tid = threadIdx.x;
    const int l = tid & 63;
    const int wv = tid >> 6;
    const int wm = wv >> 1, wn = wv & 1;
    const int quad = l >> 4, tl = l & 15;

    floatx4 acc[4][4];
#pragma unroll
    for (int i = 0; i < 4; ++i)
#pragma unroll
        for (int j = 0; j < 4; ++j)
#pragma unroll
            for (int r = 0; r < 4; ++r) acc[i][j][r] = 0.f;

    // staging assignments: 512 16B-chunks per tile, chunkid = c*256 + tid
    const ushort_t* agp[2];
    const ushort_t* bgp[2];
    ushort_t* alds[2];
    ushort_t* blds[2];
#pragma unroll
    for (int c = 0; c < 2; ++c) {
        int chunk = c * 256 + tid;
        int row = chunk >> 2, cc = chunk & 3;
        int rowc = m0 + row; if (rowc >= ne) rowc = ne - 1;   // clamp tail rows
        size_t arow = GATHER ? (size_t)token_list[aoff + rowc] : (size_t)(aoff + rowc);
        agp[c] = A + arow * KDIM + cc * 8;
        bgp[c] = Bw + (size_t)(n0 + row) * KDIM + cc * 8;
        int base = (c * 256 + (tid & ~63)) * 8;               // wave-uniform LDS base (elems)
        alds[c] = &As[base];
        blds[c] = &Bs[base];
    }

    for (int k0 = 0; k0 < KDIM; k0 += 32) {
        gload16(agp[0] + k0, alds[0]);
        gload16(agp[1] + k0, alds[1]);
        gload16(bgp[0] + k0, blds[0]);
        gload16(bgp[1] + k0, blds[1]);
        __syncthreads();   // drains vmcnt: LDS tiles complete
        short8 a[4], b[4];
#pragma unroll
        for (int i = 0; i < 4; ++i)
            a[i] = *(const short8*)&As[(wm * 64 + i * 16 + tl) * 32 + quad * 8];
#pragma unroll
        for (int j = 0; j < 4; ++j)
            b[j] = *(const short8*)&Bs[(wn * 64 + j * 16 + tl) * 32 + quad * 8];
#pragma unroll
        for (int i = 0; i < 4; ++i)
#pragma unroll
            for (int j = 0; j < 4; ++j)
                acc[i][j] = __builtin_amdgcn_mfma_f32_16x16x32_bf16(a[i], b[j], acc[i][j], 0, 0, 0);
        __syncthreads();   // all reads done before next stage overwrites
    }

    // epilogue: D[row = quad*4 + r][col = lane&15]
#pragma unroll
    for (int i = 0; i < 4; ++i) {
        int mrow = m0 + wm * 64 + i * 16 + quad * 4;
#pragma unroll
        for (int r = 0; r < 4; ++r) {
            int m = mrow + r;
            if (m < ne) {
                float wgt = 0.f;
                if constexpr (MODE == 2) wgt = weight_list[aoff + m];
#pragma unroll
                for (int j = 0; j < 4; ++j) {
                    int col = n0 + wn * 64 + j * 16 + tl;
                    size_t oidx = (size_t)(aoff + m) * NDIM + col;
                    float v = acc[i][j][r];
                    if constexpr (MODE == 0) {
                        float s = v / (1.f + __expf(-v));       // silu
                        Out[oidx] = f2b(s);
                    } else if constexpr (MODE == 1) {
                        float c = b2f(C1[oidx]);                // read BEFORE write (same thread)
                        Out[oidx] = f2b(v * c);
                    } else {
                        Out[oidx] = f2b(wgt * v);
                    }
                }
            }
        }
    }
}

// ---------------- final gather-sum: out[t] = Y[s0] + Y[s1], f32 out ----------------
__global__ __launch_bounds__(256) void combine_kernel(
    const ushort_t* __restrict__ Y, const int* __restrict__ slot_of,
    float* __restrict__ OutF)
{
    int idx = blockIdx.x * 256 + threadIdx.x;   // T*H/8 threads
    int t = idx >> 7;
    int h8 = (idx & 127) << 3;
    int s0 = slot_of[t * 2], s1 = slot_of[t * 2 + 1];
    short8 y0 = *(const short8*)&Y[(size_t)s0 * HDIM + h8];
    short8 y1 = *(const short8*)&Y[(size_t)s1 * HDIM + h8];
    float4 o0, o1;
    o0.x = b2f((unsigned short)y0[0]) + b2f((unsigned short)y1[0]);
    o0.y = b2f((unsigned short)y0[1]) + b2f((unsigned short)y1[1]);
    o0.z = b2f((unsigned short)y0[2]) + b2f((unsigned short)y1[2]);
    o0.w = b2f((unsigned short)y0[3]) + b2f((unsigned short)y1[3]);
    o1.x = b2f((unsigned short)y0[4]) + b2f((unsigned short)y1[4]);
    o1.y = b2f((unsigned short)y0[5]) + b2f((unsigned short)y1[5]);
    o1.z = b2f((unsigned short)y0[6]) + b2f((unsigned short)y1[6]);
    o1.w = b2f((unsigned short)y0[7]) + b2f((unsigned short)y1[7]);
    float4* dst = (float4*)&OutF[(size_t)t * HDIM + h8];
    dst[0] = o0; dst[1] = o1;
}

extern "C" void kernel_launch(void* const* d_in, const int* in_sizes, int n_in,
                              void* d_out, int out_size, void* d_ws, size_t ws_size,
                              hipStream_t stream)
{
    const float* X  = (const float*)d_in[0];   // [T, H] f32
    const float* GW = (const float*)d_in[1];   // [E, H] f32
    const float* W1 = (const float*)d_in[2];   // [E, F, H] f32
    const float* W3 = (const float*)d_in[3];   // [E, F, H] f32
    const float* W2 = (const float*)d_in[4];   // [E, H, F] f32
    float* OUT = (float*)d_out;                 // [T, H] f32 ++ [T, E] f32
    float* LOGITS = OUT + (size_t)T_TOK * HDIM;

    char* p = (char*)d_ws;
    auto take = [&](size_t b) { char* q = p; p += (b + 255) & ~(size_t)255; return q; };
    ushort_t* Xb = (ushort_t*)take((size_t)T_TOK * HDIM * 2);          // 16 MB bf16 X
    ushort_t* Wb = (ushort_t*)take((size_t)NEXP * FDIM * HDIM * 2);    // 33.5 MB, reused per GEMM
    ushort_t* C1 = (ushort_t*)take((size_t)TK_SLOTS * FDIM * 2);       // 64 MB (C1, then G in-place)
    ushort_t* Yb = (ushort_t*)take((size_t)TK_SLOTS * HDIM * 2);       // 32 MB
    int*   counts      = (int*)take(NEXP * 4);
    int*   offsets     = (int*)take(NEXP * 4);
    int*   cursors     = (int*)take(NEXP * 4);
    int*   tk_e        = (int*)take(TK_SLOTS * 4);
    float* tk_w        = (float*)take(TK_SLOTS * 4);
    int*   slot_of     = (int*)take(TK_SLOTS * 4);
    int*   token_list  = (int*)take(TK_SLOTS * 4);
    float* weight_list = (float*)take(TK_SLOTS * 4);

    hipMemsetAsync(counts, 0, NEXP * 4, stream);
    router_kernel<<<T_TOK / 4, 256, 0, stream>>>(X, GW, LOGITS, tk_e, tk_w, counts);
    prefix_kernel<<<1, 64, 0, stream>>>(counts, offsets, cursors);
    scatter_kernel<<<T_TOK / 256, 256, 0, stream>>>(tk_e, tk_w, offsets, cursors,
                                                    token_list, weight_list, slot_of);
    cvt_kernel<<<(T_TOK * HDIM / 8) / 256, 256, 0, stream>>>(X, Xb, T_TOK * HDIM / 8);

    cvt_kernel<<<(NEXP * FDIM * HDIM / 8) / 256, 256, 0, stream>>>(W1, Wb, NEXP * FDIM * HDIM / 8);
    moe_gemm<0, FDIM, HDIM, true ><<<dim3(FDIM / 128, T_TOK / 128, NEXP), 256, 0, stream>>>(
        Xb, Wb, counts, offsets, token_list, nullptr, nullptr, C1);

    cvt_kernel<<<(NEXP * FDIM * HDIM / 8) / 256, 256, 0, stream>>>(W3, Wb, NEXP * FDIM * HDIM / 8);
    moe_gemm<1, FDIM, HDIM, true ><<<dim3(FDIM / 128, T_TOK / 128, NEXP), 256, 0, stream>>>(
        Xb, Wb, counts, offsets, token_list, nullptr, C1, C1 /* in-place */);

    cvt_kernel<<<(NEXP * HDIM * FDIM / 8) / 256, 256, 0, stream>>>(W2, Wb, NEXP * HDIM * FDIM / 8);
    moe_gemm<2, HDIM, FDIM, false><<<dim3(HDIM / 128, T_TOK / 128, NEXP), 256, 0, stream>>>(
        C1 /* = G */, Wb, counts, offsets, token_list, weight_list, nullptr, Yb);

    combine_kernel<<<(T_TOK * HDIM / 8) / 256, 256, 0, stream>>>(Yb, slot_of, OUT);
}

// Round 3
// 620.015 us; speedup vs baseline: 1.3516x; 1.3516x over previous
//
#include <hip/hip_runtime.h>

typedef unsigned short ushort_t;
typedef __attribute__((ext_vector_type(8))) short short8;
typedef __attribute__((ext_vector_type(4))) float floatx4;

#define T_TOK 8192
#define HDIM 1024
#define FDIM 2048
#define NEXP 8
#define TK_SLOTS (T_TOK * 2)
#define SORT_THREADS 1024
#define PER_THREAD (TK_SLOTS / SORT_THREADS)   // 16

__device__ __forceinline__ float b2f(unsigned short u) {
    union { unsigned int i; float f; } x; x.i = ((unsigned int)u) << 16; return x.f;
}
__device__ __forceinline__ unsigned short f2b(float f) {  // RNE bf16
    unsigned int u = __float_as_uint(f);
    u += 0x7FFF + ((u >> 16) & 1);
    return (unsigned short)(u >> 16);
}
__device__ __forceinline__ void gload16(const void* g, void* l) {
    // async global->LDS, 16B/lane; LDS dest = wave-uniform base + lane*16
    __builtin_amdgcn_global_load_lds((const __attribute__((address_space(1))) void*)g,
                                     (__attribute__((address_space(3))) void*)l,
                                     16, 0, 0);
}

// ---------------- f32 -> bf16 conversion (8 elems/thread) ----------------
__global__ __launch_bounds__(256) void cvt_kernel(
    const float* __restrict__ src, ushort_t* __restrict__ dst, int n8)
{
    int i = blockIdx.x * 256 + threadIdx.x;
    if (i >= n8) return;
    const float4* s4 = (const float4*)src;
    float4 a = s4[2 * i], b = s4[2 * i + 1];
    short8 o;
    o[0] = (short)f2b(a.x); o[1] = (short)f2b(a.y);
    o[2] = (short)f2b(a.z); o[3] = (short)f2b(a.w);
    o[4] = (short)f2b(b.x); o[5] = (short)f2b(b.y);
    o[6] = (short)f2b(b.z); o[7] = (short)f2b(b.w);
    *(short8*)&dst[(size_t)i * 8] = o;
}

// ---------------- router: f32 logits, softmax, top-2 (NO atomics) ----------------
__global__ __launch_bounds__(256) void router_kernel(
    const float* __restrict__ X, const float* __restrict__ GW,
    float* __restrict__ logits_out, int* __restrict__ tk_e,
    float* __restrict__ tk_w)
{
    __shared__ __align__(16) float gw[NEXP * HDIM];   // 32 KB
    const int tid = threadIdx.x;
#pragma unroll
    for (int c = 0; c < 8; ++c) {
        int idx = (c * 256 + tid) * 4;
        *(float4*)&gw[idx] = *(const float4*)&GW[idx];
    }
    __syncthreads();
    const int w = tid >> 6, l = tid & 63;
    const int t = blockIdx.x * 4 + w;
    float acc[NEXP];
#pragma unroll
    for (int e = 0; e < NEXP; ++e) acc[e] = 0.f;
#pragma unroll
    for (int it = 0; it < 4; ++it) {
        const int colb = it * 256 + l * 4;
        float4 xv = *(const float4*)&X[(size_t)t * HDIM + colb];
#pragma unroll
        for (int e = 0; e < NEXP; ++e) {
            float4 gv = *(const float4*)&gw[e * HDIM + colb];
            acc[e] += xv.x * gv.x + xv.y * gv.y + xv.z * gv.z + xv.w * gv.w;
        }
    }
#pragma unroll
    for (int off = 32; off >= 1; off >>= 1)
#pragma unroll
        for (int e = 0; e < NEXP; ++e) acc[e] += __shfl_xor(acc[e], off, 64);

    if (l == 0) {
        float mx = acc[0];
#pragma unroll
        for (int e = 1; e < NEXP; ++e) mx = fmaxf(mx, acc[e]);
        float p[NEXP];
#pragma unroll
        for (int e = 0; e < NEXP; ++e) p[e] = __expf(acc[e] - mx);
        int e0 = 0;
#pragma unroll
        for (int e = 1; e < NEXP; ++e) if (p[e] > p[e0]) e0 = e;  // strict >: lower idx wins ties
        int e1 = (e0 == 0) ? 1 : 0;
#pragma unroll
        for (int e = 0; e < NEXP; ++e) if (e != e0 && p[e] > p[e1]) e1 = e;
        float den = p[e0] + p[e1];
        tk_e[t * 2] = e0; tk_e[t * 2 + 1] = e1;
        tk_w[t * 2] = p[e0] / den; tk_w[t * 2 + 1] = p[e1] / den;
#pragma unroll
        for (int e = 0; e < NEXP; ++e) logits_out[(size_t)t * NEXP + e] = acc[e];
    }
}

// ---------------- single-block deterministic histogram+scan+scatter ----------------
// Replaces atomic counts/cursors: zero global atomics, replay-deterministic.
__global__ __launch_bounds__(SORT_THREADS) void sort_kernel(
    const int* __restrict__ tk_e, const float* __restrict__ tk_w,
    int* __restrict__ counts, int* __restrict__ offsets,
    int* __restrict__ token_list, float* __restrict__ weight_list,
    int* __restrict__ slot_of)
{
    __shared__ int hist[NEXP][SORT_THREADS];   // 32 KB
    __shared__ int offs[NEXP];
    const int thr = threadIdx.x;
    const int base = thr * PER_THREAD;

    int ev[PER_THREAD];
    int cnt[NEXP];
#pragma unroll
    for (int e = 0; e < NEXP; ++e) cnt[e] = 0;
#pragma unroll
    for (int i = 0; i < PER_THREAD; ++i) {
        ev[i] = tk_e[base + i];
#pragma unroll
        for (int e = 0; e < NEXP; ++e) cnt[e] += (ev[i] == e);
    }
#pragma unroll
    for (int e = 0; e < NEXP; ++e) hist[e][thr] = cnt[e];
    __syncthreads();

    // Hillis-Steele inclusive scan over threads, all 8 experts in parallel
    for (int off = 1; off < SORT_THREADS; off <<= 1) {
        int v[NEXP];
#pragma unroll
        for (int e = 0; e < NEXP; ++e) v[e] = (thr >= off) ? hist[e][thr - off] : 0;
        __syncthreads();
#pragma unroll
        for (int e = 0; e < NEXP; ++e) hist[e][thr] += v[e];
        __syncthreads();
    }

    if (thr == 0) {
        int s = 0;
#pragma unroll
        for (int e = 0; e < NEXP; ++e) {
            int c = hist[e][SORT_THREADS - 1];
            offs[e] = s; offsets[e] = s; counts[e] = c; s += c;
        }
    }
    __syncthreads();

    int run[NEXP];
#pragma unroll
    for (int e = 0; e < NEXP; ++e) run[e] = offs[e] + hist[e][thr] - cnt[e];  // exclusive base

#pragma unroll
    for (int i = 0; i < PER_THREAD; ++i) {
        int e = ev[i];
        int slot = 0;
#pragma unroll
        for (int ee = 0; ee < NEXP; ++ee) if (e == ee) slot = run[ee]++;
        token_list[slot] = (base + i) >> 1;
        weight_list[slot] = tk_w[base + i];
        slot_of[base + i] = slot;
    }
}

// ---------------- grouped GEMM template (m97 structure), bf16 in/out ----------------
// C[m,n] = sum_k A[m,k] * W_e[n,k], 128x128 tile, BK=32, 4 waves at 64x64.
// MODE 0: Out = bf16(silu(acc))             (C1 = silu(X@w1^T))
// MODE 1: Out = bf16(acc * C1)              (G  = C1 * (X@w3^T)) -- may run in-place on C1
// MODE 2: Out = bf16(weight[row] * acc)     (Y  = w_route * (G@w2^T))
template <int MODE, int NDIM, int KDIM, bool GATHER>
__global__ __launch_bounds__(256) void moe_gemm(
    const ushort_t* __restrict__ A, const ushort_t* __restrict__ W,
    const int* __restrict__ counts, const int* __restrict__ offsets,
    const int* __restrict__ token_list, const float* __restrict__ weight_list,
    const ushort_t* C1, ushort_t* Out)   // no __restrict__: MODE 1 aliases C1 == Out
{
    const int e = blockIdx.z;
    const int ne = counts[e];
    const int m0 = blockIdx.y * 128;
    if (m0 >= ne) return;
    const int n0 = blockIdx.x * 128;
    const int aoff = offsets[e];
    const ushort_t* Bw = W + (size_t)e * NDIM * KDIM;

    __shared__ __align__(16) ushort_t As[128 * 32];
    __shared__ __align__(16) ushort_t Bs[128 * 32];

    const int tid = threadIdx.x;
    const int l = tid & 63;
    const int wv = tid >> 6;
    const int wm = wv >> 1, wn = wv & 1;
    const int quad = l >> 4, tl = l & 15;

    floatx4 acc[4][4];
#pragma unroll
    for (int i = 0; i < 4; ++i)
#pragma unroll
        for (int j = 0; j < 4; ++j)
#pragma unroll
            for (int r = 0; r < 4; ++r) acc[i][j][r] = 0.f;

    // staging assignments: 512 16B-chunks per tile, chunkid = c*256 + tid
    const ushort_t* agp[2];
    const ushort_t* bgp[2];
    ushort_t* alds[2];
    ushort_t* blds[2];
#pragma unroll
    for (int c = 0; c < 2; ++c) {
        int chunk = c * 256 + tid;
        int row = chunk >> 2, cc = chunk & 3;
        int rowc = m0 + row; if (rowc >= ne) rowc = ne - 1;   // clamp tail rows
        size_t arow = GATHER ? (size_t)token_list[aoff + rowc] : (size_t)(aoff + rowc);
        agp[c] = A + arow * KDIM + cc * 8;
        bgp[c] = Bw + (size_t)(n0 + row) * KDIM + cc * 8;
        int base = (c * 256 + (tid & ~63)) * 8;               // wave-uniform LDS base (elems)
        alds[c] = &As[base];
        blds[c] = &Bs[base];
    }

    for (int k0 = 0; k0 < KDIM; k0 += 32) {
        gload16(agp[0] + k0, alds[0]);
        gload16(agp[1] + k0, alds[1]);
        gload16(bgp[0] + k0, blds[0]);
        gload16(bgp[1] + k0, blds[1]);
        __syncthreads();   // drains vmcnt: LDS tiles complete
        short8 a[4], b[4];
#pragma unroll
        for (int i = 0; i < 4; ++i)
            a[i] = *(const short8*)&As[(wm * 64 + i * 16 + tl) * 32 + quad * 8];
#pragma unroll
        for (int j = 0; j < 4; ++j)
            b[j] = *(const short8*)&Bs[(wn * 64 + j * 16 + tl) * 32 + quad * 8];
#pragma unroll
        for (int i = 0; i < 4; ++i)
#pragma unroll
            for (int j = 0; j < 4; ++j)
                acc[i][j] = __builtin_amdgcn_mfma_f32_16x16x32_bf16(a[i], b[j], acc[i][j], 0, 0, 0);
        __syncthreads();   // all reads done before next stage overwrites
    }

    // epilogue: D[row = quad*4 + r][col = lane&15]
#pragma unroll
    for (int i = 0; i < 4; ++i) {
        int mrow = m0 + wm * 64 + i * 16 + quad * 4;
#pragma unroll
        for (int r = 0; r < 4; ++r) {
            int m = mrow + r;
            if (m < ne) {
                float wgt = 0.f;
                if constexpr (MODE == 2) wgt = weight_list[aoff + m];
#pragma unroll
                for (int j = 0; j < 4; ++j) {
                    int col = n0 + wn * 64 + j * 16 + tl;
                    size_t oidx = (size_t)(aoff + m) * NDIM + col;
                    float v = acc[i][j][r];
                    if constexpr (MODE == 0) {
                        float s = v / (1.f + __expf(-v));       // silu
                        Out[oidx] = f2b(s);
                    } else if constexpr (MODE == 1) {
                        float c = b2f(C1[oidx]);                // read BEFORE write (same thread)
                        Out[oidx] = f2b(v * c);
                    } else {
                        Out[oidx] = f2b(wgt * v);
                    }
                }
            }
        }
    }
}

// ---------------- final gather-sum: out[t] = Y[s0] + Y[s1], f32 out ----------------
__global__ __launch_bounds__(256) void combine_kernel(
    const ushort_t* __restrict__ Y, const int* __restrict__ slot_of,
    float* __restrict__ OutF)
{
    int idx = blockIdx.x * 256 + threadIdx.x;   // T*H/8 threads
    int t = idx >> 7;
    int h8 = (idx & 127) << 3;
    int s0 = slot_of[t * 2], s1 = slot_of[t * 2 + 1];
    short8 y0 = *(const short8*)&Y[(size_t)s0 * HDIM + h8];
    short8 y1 = *(const short8*)&Y[(size_t)s1 * HDIM + h8];
    float4 o0, o1;
    o0.x = b2f((unsigned short)y0[0]) + b2f((unsigned short)y1[0]);
    o0.y = b2f((unsigned short)y0[1]) + b2f((unsigned short)y1[1]);
    o0.z = b2f((unsigned short)y0[2]) + b2f((unsigned short)y1[2]);
    o0.w = b2f((unsigned short)y0[3]) + b2f((unsigned short)y1[3]);
    o1.x = b2f((unsigned short)y0[4]) + b2f((unsigned short)y1[4]);
    o1.y = b2f((unsigned short)y0[5]) + b2f((unsigned short)y1[5]);
    o1.z = b2f((unsigned short)y0[6]) + b2f((unsigned short)y1[6]);
    o1.w = b2f((unsigned short)y0[7]) + b2f((unsigned short)y1[7]);
    float4* dst = (float4*)&OutF[(size_t)t * HDIM + h8];
    dst[0] = o0; dst[1] = o1;
}

extern "C" void kernel_launch(void* const* d_in, const int* in_sizes, int n_in,
                              void* d_out, int out_size, void* d_ws, size_t ws_size,
                              hipStream_t stream)
{
    const float* X  = (const float*)d_in[0];   // [T, H] f32
    const float* GW = (const float*)d_in[1];   // [E, H] f32
    const float* W1 = (const float*)d_in[2];   // [E, F, H] f32
    const float* W3 = (const float*)d_in[3];   // [E, F, H] f32
    const float* W2 = (const float*)d_in[4];   // [E, H, F] f32
    float* OUT = (float*)d_out;                 // [T, H] f32 ++ [T, E] f32
    float* LOGITS = OUT + (size_t)T_TOK * HDIM;

    char* p = (char*)d_ws;
    auto take = [&](size_t b) { char* q = p; p += (b + 255) & ~(size_t)255; return q; };
    ushort_t* Xb = (ushort_t*)take((size_t)T_TOK * HDIM * 2);          // 16 MB bf16 X
    ushort_t* Wb = (ushort_t*)take((size_t)NEXP * FDIM * HDIM * 2);    // 33.5 MB, reused per GEMM
    ushort_t* C1 = (ushort_t*)take((size_t)TK_SLOTS * FDIM * 2);       // 64 MB (C1, then G in-place)
    ushort_t* Yb = (ushort_t*)take((size_t)TK_SLOTS * HDIM * 2);       // 32 MB
    int*   counts      = (int*)take(NEXP * 4);
    int*   offsets     = (int*)take(NEXP * 4);
    int*   tk_e        = (int*)take(TK_SLOTS * 4);
    float* tk_w        = (float*)take(TK_SLOTS * 4);
    int*   slot_of     = (int*)take(TK_SLOTS * 4);
    int*   token_list  = (int*)take(TK_SLOTS * 4);
    float* weight_list = (float*)take(TK_SLOTS * 4);

    router_kernel<<<T_TOK / 4, 256, 0, stream>>>(X, GW, LOGITS, tk_e, tk_w);
    sort_kernel<<<1, SORT_THREADS, 0, stream>>>(tk_e, tk_w, counts, offsets,
                                                token_list, weight_list, slot_of);
    cvt_kernel<<<(T_TOK * HDIM / 8) / 256, 256, 0, stream>>>(X, Xb, T_TOK * HDIM / 8);

    cvt_kernel<<<(NEXP * FDIM * HDIM / 8) / 256, 256, 0, stream>>>(W1, Wb, NEXP * FDIM * HDIM / 8);
    moe_gemm<0, FDIM, HDIM, true ><<<dim3(FDIM / 128, T_TOK / 128, NEXP), 256, 0, stream>>>(
        Xb, Wb, counts, offsets, token_list, nullptr, nullptr, C1);

    cvt_kernel<<<(NEXP * FDIM * HDIM / 8) / 256, 256, 0, stream>>>(W3, Wb, NEXP * FDIM * HDIM / 8);
    moe_gemm<1, FDIM, HDIM, true ><<<dim3(FDIM / 128, T_TOK / 128, NEXP), 256, 0, stream>>>(
        Xb, Wb, counts, offsets, token_list, nullptr, C1, C1 /* in-place */);

    cvt_kernel<<<(NEXP * HDIM * FDIM / 8) / 256, 256, 0, stream>>>(W2, Wb, NEXP * HDIM * FDIM / 8);
    moe_gemm<2, HDIM, FDIM, false><<<dim3(HDIM / 128, T_TOK / 128, NEXP), 256, 0, stream>>>(
        C1 /* = G */, Wb, counts, offsets, token_list, weight_list, nullptr, Yb);

    combine_kernel<<<(T_TOK * HDIM / 8) / 256, 256, 0, stream>>>(Yb, slot_of, OUT);
}